// Round 2
// 1614.495 us; speedup vs baseline: 1.1118x; 1.1118x over previous
//
#include <hip/hip_runtime.h>
#include <hip/hip_bf16.h>
#include <stdint.h>

typedef __hip_bfloat16 bf16;
typedef __attribute__((ext_vector_type(8))) short v8s;   // 8 x bf16 (4 VGPR) MFMA frag
typedef __attribute__((ext_vector_type(4))) float v4f;   // MFMA accum

#define NPTS 32768
#define KTOT 2336      // TOTAL features (= K of the big GEMM, 73 x 32)
#define MPH2 2432      // padded per-half column count (19 x 128)
#define NBX2 19        // column tiles (MPH2/128)

#define AS1C(p) ((const __attribute__((address_space(1))) void*)(p))
#define AS3(p)  ((__attribute__((address_space(3))) void*)(p))

__device__ __forceinline__ float sigm(float x){ return 1.0f/(1.0f + expf(-x)); }
__device__ __forceinline__ float gelu_tanh(float x){
  // precise form — used in preamble only (index-critical path)
  float u = 0.7978845608028654f*(x + 0.044715f*x*x*x);
  return 0.5f*x*(1.0f + tanhf(u));
}
__device__ __forceinline__ float gelu_fast(float x){
  // identical math: 0.5x(1+tanh(u)) == x*sigmoid(2u); __expf err ~1e-5 rel
  float u = 1.5957691216057308f*x*(1.0f + 0.044715f*x*x);
  return x / (1.0f + __expf(-u));
}

// ---------------------------------------------------------------- preamble MLP
__global__ __launch_bounds__(256) void k_preamble(
    const float* __restrict__ pos, const float* __restrict__ t,
    const float* __restrict__ sph_proj, const float* __restrict__ tb1,
    const float* __restrict__ tb2,
    const float* __restrict__ gn1, const float* __restrict__ gw1,
    const float* __restrict__ gn2, const float* __restrict__ gw2,
    const float* __restrict__ gn3, const float* __restrict__ gw3,
    float4* __restrict__ Pbuf)
{
  int i = blockIdx.x*256 + threadIdx.x;
  if(i >= NPTS) return;
  float px = pos[3*i], py = pos[3*i+1], pz = pos[3*i+2];
  float rho = sqrtf(px*px + py*py + pz*pz);
  float phi = atan2f(py, px);
  float cz = fminf(1.0f, fmaxf(-1.0f, pz/rho));
  float theta = acosf(cz);
  float tv = t[i];
  float h[12];
  #pragma unroll
  for(int j=0;j<8;j++)
    h[j] = rho*sph_proj[j] + phi*sph_proj[8+j] + theta*sph_proj[16+j];
  float ct = cosf(tv + tb1[0]);
  float st = sinf(tv + tb2[0]);
  h[8]=ct; h[9]=st; h[10]=ct*sigm(ct); h[11]=st*sigm(st);

  float ss = 0.f;
  #pragma unroll
  for(int j=0;j<12;j++) ss += h[j]*h[j];
  float den = sqrtf(ss/12.0f) + 1e-8f;
  float hn[12];
  #pragma unroll
  for(int j=0;j<12;j++) hn[j] = gn1[j]*h[j]/den;

  float h2[16];
  #pragma unroll
  for(int j=0;j<16;j++){
    float a=0.f, g=0.f;
    #pragma unroll
    for(int k=0;k<12;k++){ a += hn[k]*gw1[k*32+j]; g += hn[k]*gw1[k*32+16+j]; }
    h2[j] = a*gelu_tanh(g);
  }
  ss = 0.f;
  #pragma unroll
  for(int j=0;j<16;j++) ss += h2[j]*h2[j];
  den = sqrtf(ss/16.0f) + 1e-8f;
  float hn2[16];
  #pragma unroll
  for(int j=0;j<16;j++) hn2[j] = gn2[j]*h2[j]/den;

  float h3[16];
  #pragma unroll
  for(int j=0;j<16;j++){
    float a=0.f, g=0.f;
    #pragma unroll
    for(int k=0;k<16;k++){ a += hn2[k]*gw2[k*32+j]; g += hn2[k]*gw2[k*32+16+j]; }
    h3[j] = a*gelu_tanh(g);
  }
  ss = 0.f;
  #pragma unroll
  for(int j=0;j<16;j++) ss += h3[j]*h3[j];
  den = sqrtf(ss/16.0f) + 1e-8f;
  float q[3];
  #pragma unroll
  for(int j=0;j<3;j++){
    float a=0.f;
    #pragma unroll
    for(int k=0;k<16;k++) a += (gn3[k]*h3[k]/den)*gw3[k*3+j];
    q[j] = sigm(a);
  }
  Pbuf[i] = make_float4(q[0], q[1], q[2], tv);
}

// ---------------------------------------------------------------- table gather
// lane-packed row copy: for F<64, 64/F rows per pass (full lane utilization)
template<int F, int R>
__device__ __forceinline__ float rows_copyT(const float* __restrict__ T,
    const int (&offs)[R], bf16* __restrict__ dst, int lane){
  float ss = 0.f;
  if constexpr (F >= 64){
    #pragma unroll
    for(int r=0;r<R;r++){
      #pragma unroll
      for(int f0=0; f0<F; f0+=64){
        float v = T[(size_t)offs[r] + f0 + lane];
        dst[r*F + f0 + lane] = __float2bfloat16(v);
        ss += v*v;
      }
    }
  } else {
    constexpr int RPP = 64/F;
    int sub = lane / F;
    int f   = lane & (F-1);
    #pragma unroll
    for(int r0=0;r0<R;r0+=RPP){
      int r = r0 + sub;
      if(r < R){
        float v = T[(size_t)offs[r] + f];
        dst[r*F + f] = __float2bfloat16(v);
        ss += v*v;
      }
    }
  }
  return ss;
}

template<int F>
__device__ __forceinline__ float table3_gather(const float* __restrict__ T, int d,
    float p0, float p1, float p2, bf16* __restrict__ dst, int lane){
  int ix = (int)(p0*(float)(d-1));
  int iy = (int)(p1*(float)(d-1));
  int iz = (int)(p2*(float)(d-1));
  int xp = (ix+1>=d)?0:ix+1, xm = (ix==0)?d-1:ix-1;
  int yp = (iy+1>=d)?0:iy+1, ym = (iy==0)?d-1:iy-1;
  int zp = (iz+1>=d)?0:iz+1, zm = (iz==0)?d-1:iz-1;
  int offs[7] = {
    ((ix*d+iy)*d+iz)*F, ((xp*d+iy)*d+iz)*F, ((xm*d+iy)*d+iz)*F,
    ((ix*d+yp)*d+iz)*F, ((ix*d+ym)*d+iz)*F,
    ((ix*d+iy)*d+zp)*F, ((ix*d+iy)*d+zm)*F };
  return rows_copyT<F,7>(T, offs, dst, lane);
}

template<int F>
__device__ __forceinline__ float table4_gather(const float* __restrict__ T,
    int d0,int d1,int d2,int d3,
    float p0,float p1,float p2,float p3, bf16* __restrict__ dst, int lane){
  int ix = (int)(p0*(float)(d0-1));
  int iy = (int)(p1*(float)(d1-1));
  int iz = (int)(p2*(float)(d2-1));
  int iw = (int)(p3*(float)(d3-1));
  int xp=(ix+1>=d0)?0:ix+1, xm=(ix==0)?d0-1:ix-1;
  int yp=(iy+1>=d1)?0:iy+1, ym=(iy==0)?d1-1:iy-1;
  int zp=(iz+1>=d2)?0:iz+1, zm=(iz==0)?d2-1:iz-1;
  int wp=(iw+1>=d3)?0:iw+1, wm=(iw==0)?d3-1:iw-1;
  #define RO(x,y,z,w) (((((x)*d1 + (y))*d2 + (z))*d3 + (w))*F)
  int offs[9] = {
    RO(ix,iy,iz,iw), RO(xp,iy,iz,iw), RO(xm,iy,iz,iw),
    RO(ix,yp,iz,iw), RO(ix,ym,iz,iw), RO(ix,iy,zp,iw), RO(ix,iy,zm,iw),
    RO(ix,iy,iz,wp), RO(ix,iy,iz,wm) };
  #undef RO
  return rows_copyT<F,9>(T, offs, dst, lane);
}

__global__ __launch_bounds__(256) void k_gather(
    const float4* __restrict__ Pbuf,
    const float* __restrict__ T0, const float* __restrict__ T1,
    const float* __restrict__ T2, const float* __restrict__ T3,
    const float* __restrict__ S1, const float* __restrict__ S2,
    const float* __restrict__ TF,
    bf16* __restrict__ X, float* __restrict__ sx)
{
  int wave = threadIdx.x>>6, lane = threadIdx.x&63;
  int ptid = blockIdx.x*4 + wave;
  float4 P = Pbuf[ptid];
  bf16* dst = X + (size_t)ptid*KTOT;
  float ss = 0.f;
  ss += table3_gather<16 >(T0, 128, P.x, P.y, P.z, dst + 0,    lane);
  ss += table3_gather<32 >(T1,  64, P.x, P.y, P.z, dst + 112,  lane);
  ss += table3_gather<64 >(T2,  32, P.x, P.y, P.z, dst + 336,  lane);
  ss += table3_gather<128>(T3,  16, P.x, P.y, P.z, dst + 784,  lane);
  ss += table4_gather<64>(S1, 16,16,16,64, P.x,P.y,P.z,P.w, dst + 1680, lane);
  ss += table4_gather<8 >(S2, 64,64,32,16, P.x,P.y,P.z,P.w, dst + 2256, lane);
  {
    int ix=(int)(P.x*3.0f), iy=(int)(P.y*3.0f), iz=(int)(P.z*3.0f);
    int iw=(int)(P.w*65535.0f);
    int offs[1] = { (int)((((ix*4+iy)*4+iz))*65536 + iw)*8 };
    ss += rows_copyT<8,1>(TF, offs, dst + 2328, lane);
  }
  #pragma unroll
  for(int o=32;o>0;o>>=1) ss += __shfl_xor(ss, o);
  if(lane==0) sx[ptid] = 1.0f/(sqrtf(ss/2336.0f) + 1e-8f);
}

// ----------------------------------------- W1b zero-fill (covers column pads)
// exact count: 2*MPH2*KTOT bf16 = 1,420,160 uint4 — guard against overrun
#define W1B_U4 ((2*MPH2*KTOT*2)/16)
__global__ __launch_bounds__(256) void k_w1zero(uint4* __restrict__ W1b){
  size_t idx = (size_t)blockIdx.x*256 + threadIdx.x;
  if(idx < (size_t)W1B_U4)
    W1b[idx] = make_uint4(0u,0u,0u,0u);
}

// ------------------------------------------- W1 prep: transpose+scale+bf16
__global__ __launch_bounds__(256) void k_w1prep(const float* __restrict__ vw1,
                                                const float* __restrict__ vn1,
                                                bf16* __restrict__ W1b)
{
  __shared__ float tile[32][33];
  int h  = blockIdx.z;
  int m0 = blockIdx.x*32, k0 = blockIdx.y*32;
  int tx = threadIdx.x & 31, ty = threadIdx.x >> 5;   // 32 x 8
  #pragma unroll
  for(int dy=0; dy<32; dy+=8){
    int k = k0 + ty + dy;
    tile[ty+dy][tx] = vw1[(size_t)k*4672 + h*2336 + m0 + tx] * vn1[k];
  }
  __syncthreads();
  #pragma unroll
  for(int dy=0; dy<32; dy+=8){
    int m = m0 + ty + dy;
    W1b[(size_t)(h*MPH2 + m)*KTOT + k0 + tx] = __float2bfloat16(tile[tx][ty+dy]);
  }
}

// ---------------------- W2f prep: vn2 (.) vw2 @ fw[0:64]  -> (2336 x 4) fp32
__global__ __launch_bounds__(256) void k_w2prep(const float* __restrict__ vw2,
                                                const float* __restrict__ vn2,
                                                const float* __restrict__ fw,
                                                float4* __restrict__ W2f)
{
  int k = blockIdx.x*256 + threadIdx.x;
  if(k >= KTOT) return;
  float a0=0,a1=0,a2=0,a3=0;
  for(int i=0;i<64;i++){
    float w = vw2[k*64+i];
    a0 += w*fw[i*4+0]; a1 += w*fw[i*4+1]; a2 += w*fw[i*4+2]; a3 += w*fw[i*4+3];
  }
  float s = vn2[k];
  W2f[k] = make_float4(s*a0, s*a1, s*a2, s*a3);
}

// ===================== 256x256 counted-vmcnt pipelined GEMM =====================
// Tile: BM=256 rows x 128 phys cols x {a,g} halves (BN=256 B-rows, interleaved:
//   br = cg*64 + h*32 + c  so each wave's frag pair (j, j+2) is a GeGLU pair).
// K pipeline: BK=32, 4-buffer LDS ring, prefetch depth 3.  Per tile each wave
// issues exactly 4 global_load_lds; main-loop wait is vmcnt(8) (retires tile
// t+1, keeps 8 loads in flight across the barrier).  Tails: vmcnt(4), vmcnt(0).
// LDS chunk swizzle (proven, conflict-free): logical (row,q) at phys slot
//   row*4 + (q ^ ((row>>1)&3)); staging pre-swizzles the *global* source.

#define PIPE_WAIT(NSTR) do{                                   \
    __builtin_amdgcn_sched_barrier(0);                        \
    asm volatile("s_waitcnt vmcnt(" NSTR ")" ::: "memory");   \
    __builtin_amdgcn_s_barrier();                             \
  }while(0)

template<int SB>
__device__ __forceinline__ void stage4(const bf16* aSrc, const bf16* bSrc, int k0e,
    bf16 (&As)[4][8192], bf16 (&Bs)[4][8192], int wave)
{
  __builtin_amdgcn_global_load_lds(AS1C(aSrc + k0e),            AS3(&As[SB][wave*512]),        16, 0, 0);
  __builtin_amdgcn_global_load_lds(AS1C(aSrc + 128*KTOT + k0e), AS3(&As[SB][4096 + wave*512]), 16, 0, 0);
  __builtin_amdgcn_global_load_lds(AS1C(bSrc + k0e),            AS3(&Bs[SB][wave*512]),        16, 0, 0);
  __builtin_amdgcn_global_load_lds(AS1C(bSrc + 64*KTOT + k0e),  AS3(&Bs[SB][4096 + wave*512]), 16, 0, 0);
}

template<int RB, int SB, bool STG>
__device__ __forceinline__ void body(const bf16* aSrc, const bf16* bSrc, int k0e,
    bf16 (&As)[4][8192], bf16 (&Bs)[4][8192], int wave, int aOff, int bOff,
    v4f (&acc)[8][4])
{
  v8s af[8]; v8s bb[4];
  #pragma unroll
  for(int i=0;i<8;i++) af[i] = *(const v8s*)(&As[RB][aOff + i*512]);
  #pragma unroll
  for(int j=0;j<4;j++) bb[j] = *(const v8s*)(&Bs[RB][bOff + j*512]);
  if constexpr (STG) stage4<SB>(aSrc, bSrc, k0e, As, Bs, wave);
  #pragma unroll
  for(int i=0;i<8;i++)
    #pragma unroll
    for(int j=0;j<4;j++)
      acc[i][j] = __builtin_amdgcn_mfma_f32_16x16x32_bf16(af[i], bb[j], acc[i][j], 0,0,0);
}

__global__ __launch_bounds__(512, 2) void k_gemm1(
    const bf16* __restrict__ X, const bf16* __restrict__ W1b,
    const float* __restrict__ sx, const float4* __restrict__ W2f,
    float* __restrict__ Part)
{
  __shared__ bf16 As[4][8192];   // 4 x (256 rows x 32 k) = 64 KiB
  __shared__ bf16 Bs[4][8192];   // 4 x (256 B-rows x 32 k) = 64 KiB
  int tid = threadIdx.x;
  int wave = tid>>6, lane = tid&63;

  // bijective XCD-chunked swizzle (2432 = 8 * 304): each XCD gets 16 full
  // by-rows; within a chunk bx runs fastest so one X row-tile stays in one L2.
  int lid = blockIdx.x + 19*blockIdx.y;
  int swz = (lid & 7)*304 + (lid >> 3);
  int bx = swz % 19;
  int by = swz / 19;
  int row0 = by*256;
  int colh = bx*128;

  int wm = wave>>2, wn = wave&3;          // 2 x 4 wave grid
  int lm = lane&15, lq = lane>>4;

  v4f acc[8][4];
  #pragma unroll
  for(int i=0;i<8;i++)
    #pragma unroll
    for(int j=0;j<4;j++)
      acc[i][j] = (v4f){0.f,0.f,0.f,0.f};

  // per-thread staging sources (pre-swizzled global address, linear LDS dest)
  int r0 = tid>>2;                               // 0..127
  int qa = (tid&3) ^ ((tid>>3)&3);               // logical k-chunk for this slot
  const bf16* aSrc = X + (size_t)(row0 + r0)*KTOT + qa*8;
  const bf16* bSrc = W1b + (size_t)(((r0>>5)&1)*MPH2 + colh + (r0>>6)*32 + (r0&31))*KTOT + qa*8;

  // per-thread swizzled ds_read offsets (elements); +i*512 / +j*512 per frag
  int swz4 = lq ^ ((lm>>1)&3);
  int aOff = ((wm*128 + lm)*4 + swz4)*8;
  int bOff = ((wn*64  + lm)*4 + swz4)*8;

  // ---- prologue: prefetch tiles 0,1,2 (12 loads in flight) ----
  stage4<0>(aSrc, bSrc, 0,  As, Bs, wave);
  stage4<1>(aSrc, bSrc, 32, As, Bs, wave);
  stage4<2>(aSrc, bSrc, 64, As, Bs, wave);
  PIPE_WAIT("8");                 // tile 0 resident; tiles 1,2 in flight

  // ---- main loop: tiles 0..67 (17 x 4), staging tiles 3..70 ----
  for(int t=0; t<68; t+=4){
    int ke = (t+3)*32;
    body<0,3,true>(aSrc,bSrc,ke,    As,Bs,wave,aOff,bOff,acc); PIPE_WAIT("8");
    body<1,0,true>(aSrc,bSrc,ke+32, As,Bs,wave,aOff,bOff,acc); PIPE_WAIT("8");
    body<2,1,true>(aSrc,bSrc,ke+64, As,Bs,wave,aOff,bOff,acc); PIPE_WAIT("8");
    body<3,2,true>(aSrc,bSrc,ke+96, As,Bs,wave,aOff,bOff,acc); PIPE_WAIT("8");
  }
  // ---- tail: tiles 68..72, staging 71,72 then drain ----
  body<0,3,true >(aSrc,bSrc,71*32, As,Bs,wave,aOff,bOff,acc); PIPE_WAIT("8");
  body<1,0,true >(aSrc,bSrc,72*32, As,Bs,wave,aOff,bOff,acc); PIPE_WAIT("8");
  body<2,0,false>(aSrc,bSrc,0,     As,Bs,wave,aOff,bOff,acc); PIPE_WAIT("4");
  body<3,0,false>(aSrc,bSrc,0,     As,Bs,wave,aOff,bOff,acc); PIPE_WAIT("0");
  body<0,0,false>(aSrc,bSrc,0,     As,Bs,wave,aOff,bOff,acc);
  __syncthreads();   // full drain before LDS reuse

  // ---- epilogue: v = (sx*a)*gelu(sx*g); reduce v*W2f and v^2 per row ----
  // C/D frag mapping: col=lane&15 (-> B-row lm), row=(lane>>4)*4+reg (-> X row)
  float* red = (float*)&As[0][0];   // 256 rows x 8 floats = 8 KiB
  #pragma unroll
  for(int ph=0; ph<4; ph++){
    if(wn == ph){
      #pragma unroll
      for(int i=0;i<8;i++){
        #pragma unroll
        for(int r=0;r<4;r++){
          int lrow = wm*128 + i*16 + lq*4 + r;
          float s = sx[row0 + lrow];
          float d0=0,d1=0,d2=0,d3=0,ssq=0;
          #pragma unroll
          for(int j=0;j<2;j++){
            int c = colh + wn*32 + j*16 + lm;     // physical column
            float va = s*acc[i][j][r];            // a-half (h=0)
            float vg = s*acc[i][j+2][r];          // g-half (h=1), same c
            float v  = va * gelu_fast(vg);        // v==0 on padded cols
            int ci = c < KTOT ? c : KTOT-1;
            float4 w = W2f[ci];
            d0 += v*w.x; d1 += v*w.y; d2 += v*w.z; d3 += v*w.w;
            ssq += v*v;
          }
          #pragma unroll
          for(int o=1;o<16;o<<=1){
            d0 += __shfl_xor(d0,o); d1 += __shfl_xor(d1,o);
            d2 += __shfl_xor(d2,o); d3 += __shfl_xor(d3,o);
            ssq += __shfl_xor(ssq,o);
          }
          if(lm==0){
            if(ph==0){
              red[lrow*8+0]=d0; red[lrow*8+1]=d1; red[lrow*8+2]=d2;
              red[lrow*8+3]=d3; red[lrow*8+4]=ssq;
              red[lrow*8+5]=0.f; red[lrow*8+6]=0.f; red[lrow*8+7]=0.f;
            } else {
              red[lrow*8+0]+=d0; red[lrow*8+1]+=d1; red[lrow*8+2]+=d2;
              red[lrow*8+3]+=d3; red[lrow*8+4]+=ssq;
            }
          }
        }
      }
    }
    __syncthreads();
  }
  {
    int rr = tid >> 1, c4 = (tid & 1)*4;
    float4 val = *(float4*)&red[rr*8 + c4];
    *(float4*)&Part[((size_t)bx*NPTS + row0 + rr)*8 + c4] = val;
  }
}

// ---------------- finalize: sum partials, rmsnorm scalar, affine tail
__global__ __launch_bounds__(256) void k_finalize(const float* __restrict__ Part,
    const float4* __restrict__ Pbuf, const float* __restrict__ fw,
    const float* __restrict__ fb, float4* __restrict__ out)
{
  int row = blockIdx.x*256 + threadIdx.x;
  const float4* P4 = (const float4*)Part;
  float d0=0,d1=0,d2=0,d3=0,ss=0;
  for(int bx=0; bx<NBX2; bx++){
    size_t base = ((size_t)bx*NPTS + row)*2;
    float4 a = P4[base];
    float4 b = P4[base+1];
    d0+=a.x; d1+=a.y; d2+=a.z; d3+=a.w; ss+=b.x;
  }
  float sv = 1.0f/(sqrtf(ss/2336.0f)+1e-8f);
  float4 P = Pbuf[row];
  float o0 = sv*d0 + P.x*fw[256+0] + P.y*fw[260+0] + P.z*fw[264+0] + P.w*fw[268+0] + fb[0];
  float o1 = sv*d1 + P.x*fw[256+1] + P.y*fw[260+1] + P.z*fw[264+1] + P.w*fw[268+1] + fb[1];
  float o2 = sv*d2 + P.x*fw[256+2] + P.y*fw[260+2] + P.z*fw[264+2] + P.w*fw[268+2] + fb[2];
  float o3 = sv*d3 + P.x*fw[256+3] + P.y*fw[260+3] + P.z*fw[264+3] + P.w*fw[268+3] + fb[3];
  out[row] = make_float4(o0,o1,o2,o3);
}

// ---------------------------------------------------------------------- launch
extern "C" void kernel_launch(void* const* d_in, const int* in_sizes, int n_in,
                              void* d_out, int out_size, void* d_ws, size_t ws_size,
                              hipStream_t stream)
{
  const float* pos = (const float*)d_in[0];
  const float* t   = (const float*)d_in[2];
  const float* T0  = (const float*)d_in[3];
  const float* T1  = (const float*)d_in[4];
  const float* T2  = (const float*)d_in[5];
  const float* T3  = (const float*)d_in[6];
  const float* S1  = (const float*)d_in[7];
  const float* S2  = (const float*)d_in[8];
  const float* TF  = (const float*)d_in[9];
  const float* sph = (const float*)d_in[10];
  const float* tb1 = (const float*)d_in[11];
  const float* tb2 = (const float*)d_in[12];
  const float* gn1 = (const float*)d_in[13];
  const float* gw1 = (const float*)d_in[14];
  const float* gn2 = (const float*)d_in[15];
  const float* gw2 = (const float*)d_in[16];
  const float* gn3 = (const float*)d_in[17];
  const float* gw3 = (const float*)d_in[18];
  const float* vn1 = (const float*)d_in[19];
  const float* vw1 = (const float*)d_in[20];
  const float* vn2 = (const float*)d_in[21];
  const float* vw2 = (const float*)d_in[22];
  const float* fw  = (const float*)d_in[23];
  const float* fb  = (const float*)d_in[24];

  uint8_t* ws = (uint8_t*)d_ws;
  size_t off = 0;
  auto carve = [&](size_t bytes)->void*{
    void* pp = ws + off; off += (bytes + 255) & ~(size_t)255; return pp;
  };
  float4* Pbuf = (float4*)carve((size_t)NPTS*sizeof(float4));
  float*  sx   = (float*) carve((size_t)NPTS*sizeof(float));
  float4* W2f  = (float4*)carve((size_t)KTOT*sizeof(float4));
  bf16*   W1b  = (bf16*)  carve((size_t)2*MPH2*KTOT*sizeof(bf16));
  bf16*   X    = (bf16*)  carve((size_t)NPTS*KTOT*sizeof(bf16));
  float*  Part = (float*) carve((size_t)NBX2*NPTS*8*sizeof(float));

  k_preamble<<<NPTS/256, 256, 0, stream>>>(pos, t, sph, tb1, tb2,
                                           gn1, gw1, gn2, gw2, gn3, gw3, Pbuf);
  // W1 prep first (so any W1b-region rounding slop can never touch X)
  k_w1zero<<<(W1B_U4 + 255)/256, 256, 0, stream>>>((uint4*)W1b);
  k_w1prep<<<dim3(73,73,2), 256, 0, stream>>>(vw1, vn1, W1b);
  k_w2prep<<<(KTOT + 255)/256, 256, 0, stream>>>(vw2, vn2, fw, W2f);
  k_gather<<<NPTS/4, 256, 0, stream>>>(Pbuf, T0, T1, T2, T3, S1, S2, TF, X, sx);
  k_gemm1<<<dim3(19,128), 512, 0, stream>>>(X, W1b, sx, W2f, Part);
  k_finalize<<<NPTS/256, 256, 0, stream>>>(Part, Pbuf, fw, fb, (float4*)d_out);
}